// Round 4
// baseline (3230.611 us; speedup 1.0000x reference)
//
#include <hip/hip_runtime.h>
#include <math.h>

#define Hn   256
#define En   128
#define Vn   256
#define TPn  32
#define BTn  2048
#define NSV  8              // valid seqs per WG (B-tile is 16 wide, half used)
#define NWG  (BTn / NSV)    // 256 workgroups -> 1 per CU
#define NT   1024

typedef __attribute__((ext_vector_type(8))) short bf8v;   // 8 bf16 = one MFMA A/B frag
typedef __attribute__((ext_vector_type(4))) float f4v;    // MFMA C/D frag

__device__ __forceinline__ unsigned short bf_hi(float x) {
    unsigned u = __float_as_uint(x);
    return (unsigned short)((u + 0x7FFFu + ((u >> 16) & 1u)) >> 16);  // RNE
}
__device__ __forceinline__ float bf_f(unsigned short h) {
    return __uint_as_float(((unsigned)h) << 16);
}
__device__ __forceinline__ float sigf(float x) { return 1.0f / (1.0f + expf(-x)); }
__device__ __forceinline__ unsigned long long amax_key(float sc, int v) {
    unsigned fb = __float_as_uint(sc);
    fb = (fb & 0x80000000u) ? ~fb : (fb | 0x80000000u);   // order-preserving
    return ((unsigned long long)fb << 32) | (unsigned)(Vn - 1 - v);  // first-idx tie-break
}

// ---------------- precompute kernels ----------------

// Ptu[v*256+u] = float4{i,f,g,o}: emb[v]@Wih[g*256+u]^T + bih + bhh
__global__ void make_ptab(float4* __restrict__ Pp, const float* __restrict__ emb,
                          const float* __restrict__ Wih, const float* __restrict__ bih,
                          const float* __restrict__ bhh) {
    int v = blockIdx.x, u = threadIdx.x;
    __shared__ __align__(16) float es[En];
    if (u < En) es[u] = emb[v * En + u];
    __syncthreads();
    float a[4];
#pragma unroll
    for (int g = 0; g < 4; ++g) {
        int r = g * Hn + u;
        float acc = bih[r] + bhh[r];
        const float4* w4 = (const float4*)(Wih + r * En);
        const float4* e4 = (const float4*)es;
        for (int k = 0; k < En / 4; ++k) {
            float4 w = w4[k], x = e4[k];
            acc = fmaf(w.x, x.x, fmaf(w.y, x.y, fmaf(w.z, x.z, fmaf(w.w, x.w, acc))));
        }
        a[g] = acc;
    }
    Pp[v * Hn + u] = make_float4(a[0], a[1], a[2], a[3]);
}

// Pack Whh into MFMA A-frag order, gate-interleaved rows rho = 4*u + g.
__global__ void pack_w(unsigned short* __restrict__ Whi, unsigned short* __restrict__ Wlo,
                       const float* __restrict__ W) {   // W: [1024][256]
    int idx = blockIdx.x * 256 + threadIdx.x;           // 262144 entries
    int j = idx & 7, lane = (idx >> 3) & 63, kt = (idx >> 9) & 7, mt = idx >> 12;
    int rho = mt * 16 + (lane & 15);
    int e = kt * 32 + ((lane >> 4) << 3) + j;
    int u = rho >> 2, g = rho & 3;
    float x = W[(g * Hn + u) * Hn + e];
    unsigned short h = bf_hi(x);
    Whi[idx] = h;
    Wlo[idx] = bf_hi(x - bf_f(h));
}

// Pack fc_W (rows = vocab) into A-frag order.
__global__ void pack_fcw(unsigned short* __restrict__ Fhi, unsigned short* __restrict__ Flo,
                         const float* __restrict__ W) {  // [256][256]
    int idx = blockIdx.x * 256 + threadIdx.x;
    int j = idx & 7, lane = (idx >> 3) & 63, kt = (idx >> 9) & 7, mt = idx >> 12;
    int v = mt * 16 + (lane & 15);
    int e = kt * 32 + ((lane >> 4) << 3) + j;
    float x = W[v * Hn + e];
    unsigned short h = bf_hi(x);
    Fhi[idx] = h;
    Flo[idx] = bf_hi(x - bf_f(h));
}

// ---------------- encoder ----------------
// 256 WGs x 1024 thr (16 waves). Wave wv owns units [16wv,16wv+16); acc reg i = gate i.
// B-tile 16 wide, seqs 0..7 valid (cols 8..15 carry finite garbage, never read out).
__global__ __launch_bounds__(NT) void enc_kernel(
    const bf8v* __restrict__ Ahi, const bf8v* __restrict__ Alo,
    const float4* __restrict__ Ptu, const int* __restrict__ phon,
    const int* __restrict__ lens, float* __restrict__ h0dec) {
    const int tid = threadIdx.x, wg = blockIdx.x;
    const int ln = tid & 63, wv = tid >> 6;
    const int q = ln >> 4, s = ln & 15;
    __shared__ __align__(16) unsigned short hBhi[2][8][64][8];   // B-frag layout, dbuf
    __shared__ __align__(16) unsigned short hBlo[2][8][64][8];
    __shared__ int tokE[2][16];
    __shared__ int lensh[16];

    {   // zero h (buffer 0)
        int e4 = tid >> 4;
        int kt = e4 >> 3, lb = (((e4 & 7) >> 1) << 4) | (tid & 15), j0 = (e4 & 1) * 4;
        *(ushort4*)&hBhi[0][kt][lb][j0] = make_ushort4(0, 0, 0, 0);
        *(ushort4*)&hBlo[0][kt][lb][j0] = make_ushort4(0, 0, 0, 0);
    }
    if (tid < 16) {
        lensh[tid] = (tid < NSV) ? lens[wg * NSV + tid] : 0;
        tokE[0][tid] = (tid < NSV) ? phon[(wg * NSV + tid) * TPn + 0] : 0;
        tokE[1][tid] = 0;
    }
    __syncthreads();
    int mx = 0;
#pragma unroll
    for (int i = 0; i < NSV; ++i) mx = max(mx, lensh[i]);
    const int mylen = lensh[s];
    float carr[4] = {0.f, 0.f, 0.f, 0.f};

    for (int t = 0; t < mx; ++t) {
        const int p = t & 1;
        if (tid < NSV) {   // prefetch next step's tokens into the other slot
            int tn = (t + 1 < TPn) ? t + 1 : t;
            tokE[p ^ 1][tid] = phon[(wg * NSV + tid) * TPn + tn];
        }
        const int tok = tokE[p][s];
        const bf8v* Bhi = (const bf8v*)&hBhi[p][0][0][0];
        const bf8v* Blo = (const bf8v*)&hBlo[p][0][0][0];
        f4v acc[4];
#pragma unroll
        for (int tt = 0; tt < 4; ++tt) acc[tt] = (f4v)0.0f;
#pragma unroll
        for (int kt = 0; kt < 8; ++kt) {
            bf8v bh = Bhi[kt * 64 + ln];
            bf8v bl = Blo[kt * 64 + ln];
#pragma unroll
            for (int tt = 0; tt < 4; ++tt) {
                bf8v ah = Ahi[((wv * 4 + tt) * 8 + kt) * 64 + ln];
                bf8v al = Alo[((wv * 4 + tt) * 8 + kt) * 64 + ln];
                acc[tt] = __builtin_amdgcn_mfma_f32_16x16x32_bf16(ah, bh, acc[tt], 0, 0, 0);
                acc[tt] = __builtin_amdgcn_mfma_f32_16x16x32_bf16(ah, bl, acc[tt], 0, 0, 0);
                acc[tt] = __builtin_amdgcn_mfma_f32_16x16x32_bf16(al, bh, acc[tt], 0, 0, 0);
            }
        }
        float hv[4];
#pragma unroll
        for (int tt = 0; tt < 4; ++tt) {
            int un = 16 * wv + 4 * tt + q;
            float4 pv = Ptu[tok * Hn + un];
            float gi = sigf(acc[tt][0] + pv.x);
            float gf = sigf(acc[tt][1] + pv.y);
            float gg = tanhf(acc[tt][2] + pv.z);
            float go = sigf(acc[tt][3] + pv.w);
            carr[tt] = fmaf(gf, carr[tt], gi * gg);
            hv[tt] = go * tanhf(carr[tt]);
        }
#pragma unroll
        for (int tt = 0; tt < 4; ++tt) {   // write h into other hB buffer
            int un = 16 * wv + 4 * tt + q;
            int kt = un >> 5, kk = un & 31;
            int lb = ((kk >> 3) << 4) | s, j = kk & 7;
            unsigned short h = bf_hi(hv[tt]);
            hBhi[p ^ 1][kt][lb][j] = h;
            hBlo[p ^ 1][kt][lb][j] = bf_hi(hv[tt] - bf_f(h));
        }
        if (s < NSV && t == mylen - 1) {
#pragma unroll
            for (int tt = 0; tt < 4; ++tt)
                h0dec[(wg * NSV + s) * Hn + 16 * wv + 4 * tt + q] = hv[tt];
        }
        __syncthreads();
    }
}

// ---------------- decoder ----------------
__global__ __launch_bounds__(NT) void dec_kernel(
    const bf8v* __restrict__ Ahi, const bf8v* __restrict__ Alo,
    const bf8v* __restrict__ FAhi, const bf8v* __restrict__ FAlo,
    const float4* __restrict__ Ptu, const float* __restrict__ fcb,
    const float* __restrict__ h0dec, const int* __restrict__ sosp,
    float* __restrict__ out) {
    const int tid = threadIdx.x, wg = blockIdx.x;
    const int ln = tid & 63, wv = tid >> 6;
    const int q = ln >> 4, s = ln & 15;
    __shared__ __align__(16) unsigned short hBhi[2][8][64][8];
    __shared__ __align__(16) unsigned short hBlo[2][8][64][8];
    __shared__ __align__(16) float scx[NSV][264];     // padded score stage (8.4 KB)
    __shared__ int toks[16];
    __shared__ unsigned long long kex[NSV][16];

    {   // load h0 into hB[0]; cols 8..15 duplicate 0..7 (harmless)
        const int s_i = tid & 15, e4 = tid >> 4;
        float4 h0 = *(const float4*)&h0dec[(wg * NSV + (s_i & 7)) * Hn + e4 * 4];
        float hv4[4] = {h0.x, h0.y, h0.z, h0.w};
        int kt = e4 >> 3, lb = (((e4 & 7) >> 1) << 4) | s_i, j0 = (e4 & 1) * 4;
        ushort4 uh, ul;
        unsigned short* uhp = (unsigned short*)&uh;
        unsigned short* ulp = (unsigned short*)&ul;
#pragma unroll
        for (int i = 0; i < 4; ++i) {
            uhp[i] = bf_hi(hv4[i]);
            ulp[i] = bf_hi(hv4[i] - bf_f(uhp[i]));
        }
        *(ushort4*)&hBhi[0][kt][lb][j0] = uh;
        *(ushort4*)&hBlo[0][kt][lb][j0] = ul;
    }
    if (tid < 16) toks[tid] = sosp[0];
    const float4 fcb4 = ((const float4*)fcb)[wv * 4 + q];  // v = 16wv+4q+i
    float carr[4] = {0.f, 0.f, 0.f, 0.f};
    __syncthreads();

    bf8v bh[8];   // cached hi B-frags; holds frags of hB[t&1] at loop top
#pragma unroll
    for (int kt = 0; kt < 8; ++kt) bh[kt] = ((const bf8v*)&hBhi[0][0][0][0])[kt * 64 + ln];

    for (int t = 0; t < TPn; ++t) {
        const int p = t & 1;
        const bf8v* BloP = (const bf8v*)&hBlo[p][0][0][0];
        const int tok = toks[s];
        f4v acc[4];
#pragma unroll
        for (int tt = 0; tt < 4; ++tt) acc[tt] = (f4v)0.0f;
#pragma unroll
        for (int kt = 0; kt < 8; ++kt) {
            bf8v bl = BloP[kt * 64 + ln];
#pragma unroll
            for (int tt = 0; tt < 4; ++tt) {
                bf8v ah = Ahi[((wv * 4 + tt) * 8 + kt) * 64 + ln];
                bf8v al = Alo[((wv * 4 + tt) * 8 + kt) * 64 + ln];
                acc[tt] = __builtin_amdgcn_mfma_f32_16x16x32_bf16(ah, bh[kt], acc[tt], 0, 0, 0);
                acc[tt] = __builtin_amdgcn_mfma_f32_16x16x32_bf16(ah, bl, acc[tt], 0, 0, 0);
                acc[tt] = __builtin_amdgcn_mfma_f32_16x16x32_bf16(al, bh[kt], acc[tt], 0, 0, 0);
            }
        }
        float hv[4];
#pragma unroll
        for (int tt = 0; tt < 4; ++tt) {
            int un = 16 * wv + 4 * tt + q;
            float4 pv = Ptu[tok * Hn + un];
            float gi = sigf(acc[tt][0] + pv.x);
            float gf = sigf(acc[tt][1] + pv.y);
            float gg = tanhf(acc[tt][2] + pv.z);
            float go = sigf(acc[tt][3] + pv.w);
            carr[tt] = fmaf(gf, carr[tt], gi * gg);
            hv[tt] = go * tanhf(carr[tt]);
        }
#pragma unroll
        for (int tt = 0; tt < 4; ++tt) {
            int un = 16 * wv + 4 * tt + q;
            int kt = un >> 5, kk = un & 31;
            int lb = ((kk >> 3) << 4) | s, j = kk & 7;
            unsigned short h = bf_hi(hv[tt]);
            hBhi[p ^ 1][kt][lb][j] = h;
            hBlo[p ^ 1][kt][lb][j] = bf_hi(hv[tt] - bf_f(h));
        }
        __syncthreads();   // new h complete

        // fc: scores[v=16wv+4q+i][s]; refresh bh cache from the new buffer
        const bf8v* BhiN = (const bf8v*)&hBhi[p ^ 1][0][0][0];
        const bf8v* BloN = (const bf8v*)&hBlo[p ^ 1][0][0][0];
        f4v sacc = (f4v)0.0f;
#pragma unroll
        for (int kt = 0; kt < 8; ++kt) {
            bh[kt] = BhiN[kt * 64 + ln];
            bf8v bl = BloN[kt * 64 + ln];
            bf8v ah = FAhi[(wv * 8 + kt) * 64 + ln];
            bf8v al = FAlo[(wv * 8 + kt) * 64 + ln];
            sacc = __builtin_amdgcn_mfma_f32_16x16x32_bf16(ah, bh[kt], sacc, 0, 0, 0);
            sacc = __builtin_amdgcn_mfma_f32_16x16x32_bf16(ah, bl, sacc, 0, 0, 0);
            sacc = __builtin_amdgcn_mfma_f32_16x16x32_bf16(al, bh[kt], sacc, 0, 0, 0);
        }
        float sc[4];
        unsigned long long key = 0;
#pragma unroll
        for (int i = 0; i < 4; ++i) {
            sc[i] = sacc[i] + fcb4[i];
            unsigned long long kk = amax_key(sc[i], 16 * wv + 4 * q + i);
            key = kk > key ? kk : key;
        }
        if (s < NSV)   // stage scores to LDS (coalesced global store after barrier)
            *(float4*)&scx[s][16 * wv + 4 * q] = make_float4(sc[0], sc[1], sc[2], sc[3]);
        {
            unsigned long long o = __shfl_xor(key, 16, 64); key = o > key ? o : key;
            o = __shfl_xor(key, 32, 64); key = o > key ? o : key;
        }
        if (ln < NSV) kex[ln][wv] = key;   // ln<8 => ln==s
        __syncthreads();
        if (tid < NSV) {
            unsigned long long kk = kex[tid][0];
#pragma unroll
            for (int w = 1; w < 16; ++w) kk = (kex[tid][w] > kk) ? kex[tid][w] : kk;
            toks[tid] = (Vn - 1) - (int)(kk & 0xffffffffu);
        }
        // coalesced out store: thread tid -> seq s2=tid>>7, cols 2m..2m+1
        {
            const int s2 = tid >> 7, m = tid & 127;
            float2 v = *(const float2*)&scx[s2][2 * m];
            *(float2*)&out[((long)(wg * NSV + s2) * TPn + t) * Vn + 2 * m] = v;
        }
        __syncthreads();
    }
}

// ---------------- launch ----------------
extern "C" void kernel_launch(void* const* d_in, const int* in_sizes, int n_in,
                              void* d_out, int out_size, void* d_ws, size_t ws_size,
                              hipStream_t stream) {
    const int*   phon = (const int*)d_in[0];
    const int*   lens = (const int*)d_in[1];
    const float* emb  = (const float*)d_in[2];
    const float* eWih = (const float*)d_in[3];
    const float* eWhh = (const float*)d_in[4];
    const float* ebih = (const float*)d_in[5];
    const float* ebhh = (const float*)d_in[6];
    const float* dWih = (const float*)d_in[7];
    const float* dWhh = (const float*)d_in[8];
    const float* dbih = (const float*)d_in[9];
    const float* dbhh = (const float*)d_in[10];
    const float* fcW  = (const float*)d_in[11];
    const float* fcb  = (const float*)d_in[12];
    const int*   sos  = (const int*)d_in[13];
    float* out = (float*)d_out;

    float4*         Ptu_e = (float4*)d_ws;                        // 1 MB
    float4*         Ptu_d = Ptu_e + 65536;                        // 1 MB
    unsigned short* WhiE  = (unsigned short*)(Ptu_d + 65536);     // 512 KB
    unsigned short* WloE  = WhiE + 262144;                        // 512 KB
    unsigned short* WhiD  = WloE + 262144;                        // 512 KB
    unsigned short* WloD  = WhiD + 262144;                        // 512 KB
    unsigned short* Fhi   = WloD + 262144;                        // 128 KB
    unsigned short* Flo   = Fhi + 65536;                          // 128 KB
    float*          h0d   = (float*)(Flo + 65536);                // 2 MB

    make_ptab<<<256, 256, 0, stream>>>(Ptu_e, emb, eWih, ebih, ebhh);
    make_ptab<<<256, 256, 0, stream>>>(Ptu_d, emb, dWih, dbih, dbhh);
    pack_w<<<1024, 256, 0, stream>>>(WhiE, WloE, eWhh);
    pack_w<<<1024, 256, 0, stream>>>(WhiD, WloD, dWhh);
    pack_fcw<<<256, 256, 0, stream>>>(Fhi, Flo, fcW);
    enc_kernel<<<NWG, NT, 0, stream>>>((const bf8v*)WhiE, (const bf8v*)WloE,
                                       Ptu_e, phon, lens, h0d);
    dec_kernel<<<NWG, NT, 0, stream>>>((const bf8v*)WhiD, (const bf8v*)WloD,
                                       (const bf8v*)Fhi, (const bf8v*)Flo,
                                       Ptu_d, fcb, h0d, sos, out);
}

// Round 5
// 2408.398 us; speedup vs baseline: 1.3414x; 1.3414x over previous
//
#include <hip/hip_runtime.h>
#include <math.h>

#define Hn   256
#define En   128
#define Vn   256
#define TPn  32
#define BTn  2048
#define NSV  8              // seqs per WG
#define NWG  (BTn / NSV)    // 256 workgroups
#define NT   512            // threads per WG (8 waves)
#define HROW 272            // padded LDS row stride (floats) for h
#define SROW 264            // padded LDS row stride for score stage

// physical index within an h row: insert 4-float skew every 64 -> 4 K-chunk
// base addresses land on disjoint bank quads (conflict-free 4-addr b128 reads)
__device__ __forceinline__ int hp(int k) { return k + 4 * (k >> 6); }

__device__ __forceinline__ float sigf(float x) { return 1.0f / (1.0f + expf(-x)); }
__device__ __forceinline__ unsigned long long amax_key(float sc, int v) {
    unsigned fb = __float_as_uint(sc);
    fb = (fb & 0x80000000u) ? ~fb : (fb | 0x80000000u);   // order-preserving
    return ((unsigned long long)fb << 32) | (unsigned)(Vn - 1 - v);  // first-idx tie
}
__device__ __forceinline__ float dot4(float4 a, float4 b, float acc) {
    return fmaf(a.x, b.x, fmaf(a.y, b.y, fmaf(a.z, b.z, fmaf(a.w, b.w, acc))));
}

// ---------------- precompute kernels ----------------

// Ptu[v*256+u] = float4{i,f,g,o}: emb[v]@Wih[g*256+u]^T + bih + bhh
__global__ void make_ptab(float4* __restrict__ Pp, const float* __restrict__ emb,
                          const float* __restrict__ Wih, const float* __restrict__ bih,
                          const float* __restrict__ bhh) {
    int v = blockIdx.x, u = threadIdx.x;
    __shared__ __align__(16) float es[En];
    if (u < En) es[u] = emb[v * En + u];
    __syncthreads();
    float a[4];
#pragma unroll
    for (int g = 0; g < 4; ++g) {
        int r = g * Hn + u;
        float acc = bih[r] + bhh[r];
        const float4* w4 = (const float4*)(Wih + r * En);
        const float4* e4 = (const float4*)es;
        for (int k = 0; k < En / 4; ++k) {
            float4 w = w4[k], x = e4[k];
            acc = dot4(w, x, acc);
        }
        a[g] = acc;
    }
    Pp[v * Hn + u] = make_float4(a[0], a[1], a[2], a[3]);
}

// Wr[(j4*8+r8)*512 + u2*4+ch] = float4{ Whh[g*256+u][ch*64+4*j4 .. +3] }
// with rho = 8*u2+r8 = 4*u+g  (u = 2*u2+(r8>>2), g = r8&3).  65536 float4.
__global__ void pack_wr(float4* __restrict__ Wr, const float* __restrict__ W) {
    int idx = blockIdx.x * 256 + threadIdx.x;
    int l = idx & 511, stripe = idx >> 9;       // stripe 0..127
    int j4 = stripe >> 3, r8 = stripe & 7;
    int u2 = l >> 2, ch = l & 3;
    int u = 2 * u2 + (r8 >> 2), g = r8 & 3;
    const float* s = W + (g * Hn + u) * Hn + ch * 64 + 4 * j4;
    Wr[idx] = make_float4(s[0], s[1], s[2], s[3]);
}

// Fr[(j4*2+rf)*512 + u2*4+ch] = float4{ fcW[2*u2+rf][ch*64+4*j4 .. +3] }. 16384 f4.
__global__ void pack_fr(float4* __restrict__ Fr, const float* __restrict__ W) {
    int idx = blockIdx.x * 256 + threadIdx.x;
    int l = idx & 511, stripe = idx >> 9;       // stripe 0..31
    int j4 = stripe >> 1, rf = stripe & 1;
    int u2 = l >> 2, ch = l & 3;
    const float* s = W + (2 * u2 + rf) * Hn + ch * 64 + 4 * j4;
    Fr[idx] = make_float4(s[0], s[1], s[2], s[3]);
}

// ---------------- encoder ----------------
// 256 WGs x 512 thr. Thread (u2=tid>>2, ch=tid&3): accumulates gate rows
// 8u2..8u2+7 over K-chunk ch*64..+64 for all 8 seqs; shfl-reduce over ch;
// then owns units {2u2,2u2+1} x seqs {2ch,2ch+1} for the nonlinearity.
__global__ __launch_bounds__(NT, 2) void enc_kernel(
    const float4* __restrict__ Wr, const float4* __restrict__ Ptu,
    const int* __restrict__ phon, const int* __restrict__ lens,
    float* __restrict__ h0dec) {
    const int tid = threadIdx.x, wg = blockIdx.x;
    const int u2 = tid >> 2, ch = tid & 3;
    const int uA = 2 * u2, sA = 2 * ch, sB = 2 * ch + 1;
    __shared__ __align__(16) float hs[NSV * HROW];
    __shared__ int lsh[NSV];

    for (int i = tid; i < NSV * HROW; i += NT) hs[i] = 0.0f;
    if (tid < NSV) lsh[tid] = lens[wg * NSV + tid];
    float c00 = 0.f, c01 = 0.f, c10 = 0.f, c11 = 0.f;
    __syncthreads();
    int mx = 0;
#pragma unroll
    for (int i = 0; i < NSV; ++i) mx = max(mx, lsh[i]);
    const int lenA = lsh[sA], lenB = lsh[sB];

    for (int t = 0; t < mx; ++t) {
        const int tokA = phon[(wg * NSV + sA) * TPn + t];
        const int tokB = phon[(wg * NSV + sB) * TPn + t];
        float ag[8][8];
#pragma unroll
        for (int r = 0; r < 8; ++r)
#pragma unroll
            for (int s = 0; s < 8; ++s) ag[r][s] = 0.0f;
        const float* hb = hs + ch * 68;
#pragma unroll 4
        for (int j4 = 0; j4 < 16; ++j4) {
            float4 w[8];
#pragma unroll
            for (int r = 0; r < 8; ++r) w[r] = Wr[(j4 * 8 + r) * NT + tid];
#pragma unroll
            for (int s = 0; s < 8; ++s) {
                float4 hv = *(const float4*)&hb[s * HROW + 4 * j4];
#pragma unroll
                for (int r = 0; r < 8; ++r) ag[r][s] = dot4(w[r], hv, ag[r][s]);
            }
        }
        // reduce partials over the 4 K-chunks (ch = lane bits 0-1)
#pragma unroll
        for (int r = 0; r < 8; ++r)
#pragma unroll
            for (int s = 0; s < 8; ++s) {
                float v = ag[r][s];
                v += __shfl_xor(v, 1, 64);
                v += __shfl_xor(v, 2, 64);
                ag[r][s] = v;
            }
        // prefetch Ptu rows for this thread's cells
        float4 pA0 = Ptu[tokA * Hn + uA], pA1 = Ptu[tokA * Hn + uA + 1];
        float4 pB0 = Ptu[tokB * Hn + uA], pB1 = Ptu[tokB * Hn + uA + 1];
        __syncthreads();   // all K-reads of hs complete
        // nonlinearity: cells (uu, ss)
        float h00, h01, h10, h11;
        {
            float gi = sigf(ag[0][sA] + pA0.x), gf = sigf(ag[1][sA] + pA0.y);
            float gg = tanhf(ag[2][sA] + pA0.z), go = sigf(ag[3][sA] + pA0.w);
            c00 = fmaf(gf, c00, gi * gg); h00 = go * tanhf(c00);
        }
        {
            float gi = sigf(ag[4][sA] + pA1.x), gf = sigf(ag[5][sA] + pA1.y);
            float gg = tanhf(ag[6][sA] + pA1.z), go = sigf(ag[7][sA] + pA1.w);
            c10 = fmaf(gf, c10, gi * gg); h10 = go * tanhf(c10);
        }
        {
            float gi = sigf(ag[0][sB] + pB0.x), gf = sigf(ag[1][sB] + pB0.y);
            float gg = tanhf(ag[2][sB] + pB0.z), go = sigf(ag[3][sB] + pB0.w);
            c01 = fmaf(gf, c01, gi * gg); h01 = go * tanhf(c01);
        }
        {
            float gi = sigf(ag[4][sB] + pB1.x), gf = sigf(ag[5][sB] + pB1.y);
            float gg = tanhf(ag[6][sB] + pB1.z), go = sigf(ag[7][sB] + pB1.w);
            c11 = fmaf(gf, c11, gi * gg); h11 = go * tanhf(c11);
        }
        const int pu = hp(uA);
        *(float2*)&hs[sA * HROW + pu] = make_float2(h00, h10);
        *(float2*)&hs[sB * HROW + pu] = make_float2(h01, h11);
        if (t == lenA - 1)
            *(float2*)&h0dec[(wg * NSV + sA) * Hn + uA] = make_float2(h00, h10);
        if (t == lenB - 1)
            *(float2*)&h0dec[(wg * NSV + sB) * Hn + uA] = make_float2(h01, h11);
        __syncthreads();   // new h visible
    }
}

// ---------------- decoder ----------------
// Fused pass: iteration i computes gates(x_i) AND fc(x_i)=scores_{i-1}.
__global__ __launch_bounds__(NT, 2) void dec_kernel(
    const float4* __restrict__ Wr, const float4* __restrict__ Fr,
    const float4* __restrict__ Ptu, const float* __restrict__ fcb,
    const float* __restrict__ h0dec, const int* __restrict__ sosp,
    float* __restrict__ out) {
    const int tid = threadIdx.x, wg = blockIdx.x;
    const int u2 = tid >> 2, ch = tid & 3;
    const int uA = 2 * u2, sA = 2 * ch, sB = 2 * ch + 1;
    const int wv = tid >> 6;
    __shared__ __align__(16) float hs[NSV * HROW];
    __shared__ __align__(16) float scx[NSV * SROW];
    __shared__ unsigned long long kex[8][NSV];

    {   // stage h0 into hs
        int s = tid >> 6, k4 = (tid & 63) * 4;
        float4 v = *(const float4*)&h0dec[(wg * NSV + s) * Hn + k4];
        *(float4*)&hs[s * HROW + hp(k4)] = v;
    }
    const int sos = sosp[0];
    const float2 fb2 = *(const float2*)&fcb[uA];
    float c00 = 0.f, c01 = 0.f, c10 = 0.f, c11 = 0.f;
    __syncthreads();

    for (int i = 0; i <= TPn; ++i) {
        float ag[8][8], af[2][8];
#pragma unroll
        for (int r = 0; r < 8; ++r)
#pragma unroll
            for (int s = 0; s < 8; ++s) ag[r][s] = 0.0f;
#pragma unroll
        for (int r = 0; r < 2; ++r)
#pragma unroll
            for (int s = 0; s < 8; ++s) af[r][s] = 0.0f;
        const float* hb = hs + ch * 68;
#pragma unroll 4
        for (int j4 = 0; j4 < 16; ++j4) {
            float4 w[8];
#pragma unroll
            for (int r = 0; r < 8; ++r) w[r] = Wr[(j4 * 8 + r) * NT + tid];
            float4 f0 = Fr[(j4 * 2 + 0) * NT + tid];
            float4 f1 = Fr[(j4 * 2 + 1) * NT + tid];
#pragma unroll
            for (int s = 0; s < 8; ++s) {
                float4 hv = *(const float4*)&hb[s * HROW + 4 * j4];
#pragma unroll
                for (int r = 0; r < 8; ++r) ag[r][s] = dot4(w[r], hv, ag[r][s]);
                af[0][s] = dot4(f0, hv, af[0][s]);
                af[1][s] = dot4(f1, hv, af[1][s]);
            }
        }
#pragma unroll
        for (int r = 0; r < 8; ++r)
#pragma unroll
            for (int s = 0; s < 8; ++s) {
                float v = ag[r][s];
                v += __shfl_xor(v, 1, 64);
                v += __shfl_xor(v, 2, 64);
                ag[r][s] = v;
            }
#pragma unroll
        for (int r = 0; r < 2; ++r)
#pragma unroll
            for (int s = 0; s < 8; ++s) {
                float v = af[r][s];
                v += __shfl_xor(v, 1, 64);
                v += __shfl_xor(v, 2, 64);
                af[r][s] = v;
            }
        if (i > 0) {
            // scores_{i-1}: this thread owns v={uA,uA+1} for seqs sA,sB
            float s0A = af[0][sA] + fb2.x, s1A = af[1][sA] + fb2.y;
            float s0B = af[0][sB] + fb2.x, s1B = af[1][sB] + fb2.y;
            *(float2*)&scx[sA * SROW + uA] = make_float2(s0A, s1A);
            *(float2*)&scx[sB * SROW + uA] = make_float2(s0B, s1B);
            unsigned long long kA = amax_key(s0A, uA), kk = amax_key(s1A, uA + 1);
            if (kk > kA) kA = kk;
            unsigned long long kB = amax_key(s0B, uA), kb2 = amax_key(s1B, uA + 1);
            if (kb2 > kB) kB = kb2;
#pragma unroll
            for (int off = 4; off < 64; off <<= 1) {
                unsigned long long oA = __shfl_xor(kA, off, 64);
                unsigned long long oB = __shfl_xor(kB, off, 64);
                if (oA > kA) kA = oA;
                if (oB > kB) kB = oB;
            }
            if ((tid & 63) == ch) {   // one lane per ch-group
                kex[wv][sA] = kA;
                kex[wv][sB] = kB;
            }
        }
        __syncthreads();   // K-reads done; scx/kex published
        int tokA = sos, tokB = sos;
        if (i > 0) {
            // coalesced store of scores_{i-1}
            int s = tid >> 6, c4 = (tid & 63) * 4;
            float4 v = *(const float4*)&scx[s * SROW + c4];
            *(float4*)&out[((long)(wg * NSV + s) * TPn + (i - 1)) * Vn + c4] = v;
            unsigned long long kA = kex[0][sA], kB = kex[0][sB];
#pragma unroll
            for (int w = 1; w < 8; ++w) {
                if (kex[w][sA] > kA) kA = kex[w][sA];
                if (kex[w][sB] > kB) kB = kex[w][sB];
            }
            tokA = (Vn - 1) - (int)(kA & 0xffffffffu);
            tokB = (Vn - 1) - (int)(kB & 0xffffffffu);
        }
        if (i < TPn) {
            float4 pA0 = Ptu[tokA * Hn + uA], pA1 = Ptu[tokA * Hn + uA + 1];
            float4 pB0 = Ptu[tokB * Hn + uA], pB1 = Ptu[tokB * Hn + uA + 1];
            float h00, h01, h10, h11;
            {
                float gi = sigf(ag[0][sA] + pA0.x), gf = sigf(ag[1][sA] + pA0.y);
                float gg = tanhf(ag[2][sA] + pA0.z), go = sigf(ag[3][sA] + pA0.w);
                c00 = fmaf(gf, c00, gi * gg); h00 = go * tanhf(c00);
            }
            {
                float gi = sigf(ag[4][sA] + pA1.x), gf = sigf(ag[5][sA] + pA1.y);
                float gg = tanhf(ag[6][sA] + pA1.z), go = sigf(ag[7][sA] + pA1.w);
                c10 = fmaf(gf, c10, gi * gg); h10 = go * tanhf(c10);
            }
            {
                float gi = sigf(ag[0][sB] + pB0.x), gf = sigf(ag[1][sB] + pB0.y);
                float gg = tanhf(ag[2][sB] + pB0.z), go = sigf(ag[3][sB] + pB0.w);
                c01 = fmaf(gf, c01, gi * gg); h01 = go * tanhf(c01);
            }
            {
                float gi = sigf(ag[4][sB] + pB1.x), gf = sigf(ag[5][sB] + pB1.y);
                float gg = tanhf(ag[6][sB] + pB1.z), go = sigf(ag[7][sB] + pB1.w);
                c11 = fmaf(gf, c11, gi * gg); h11 = go * tanhf(c11);
            }
            const int pu = hp(uA);
            *(float2*)&hs[sA * HROW + pu] = make_float2(h00, h10);
            *(float2*)&hs[sB * HROW + pu] = make_float2(h01, h11);
        }
        __syncthreads();   // new h visible
    }
}

// ---------------- launch ----------------
extern "C" void kernel_launch(void* const* d_in, const int* in_sizes, int n_in,
                              void* d_out, int out_size, void* d_ws, size_t ws_size,
                              hipStream_t stream) {
    const int*   phon = (const int*)d_in[0];
    const int*   lens = (const int*)d_in[1];
    const float* emb  = (const float*)d_in[2];
    const float* eWih = (const float*)d_in[3];
    const float* eWhh = (const float*)d_in[4];
    const float* ebih = (const float*)d_in[5];
    const float* ebhh = (const float*)d_in[6];
    const float* dWih = (const float*)d_in[7];
    const float* dWhh = (const float*)d_in[8];
    const float* dbih = (const float*)d_in[9];
    const float* dbhh = (const float*)d_in[10];
    const float* fcW  = (const float*)d_in[11];
    const float* fcb  = (const float*)d_in[12];
    const int*   sos  = (const int*)d_in[13];
    float* out = (float*)d_out;

    float4* Ptu_e = (float4*)d_ws;           // 65536 f4 = 1 MB
    float4* Ptu_d = Ptu_e + 65536;           // 1 MB
    float4* Wr_e  = Ptu_d + 65536;           // 65536 f4 = 1 MB
    float4* Wr_d  = Wr_e + 65536;            // 1 MB
    float4* Fr    = Wr_d + 65536;            // 16384 f4 = 256 KB
    float*  h0d   = (float*)(Fr + 16384);    // 2048*256 floats = 2 MB

    make_ptab<<<256, 256, 0, stream>>>(Ptu_e, emb, eWih, ebih, ebhh);
    make_ptab<<<256, 256, 0, stream>>>(Ptu_d, emb, dWih, dbih, dbhh);
    pack_wr<<<256, 256, 0, stream>>>(Wr_e, eWhh);
    pack_wr<<<256, 256, 0, stream>>>(Wr_d, dWhh);
    pack_fr<<<64, 256, 0, stream>>>(Fr, fcW);
    enc_kernel<<<NWG, NT, 0, stream>>>(Wr_e, Ptu_e, phon, lens, h0d);
    dec_kernel<<<NWG, NT, 0, stream>>>(Wr_d, Fr, Ptu_d, fcb, h0d, sos, out);
}

// Round 6
// 1469.572 us; speedup vs baseline: 2.1983x; 1.6388x over previous
//
#include <hip/hip_runtime.h>
#include <math.h>

#define Hn   256
#define En   128
#define Vn   256
#define TPn  32
#define BTn  2048
#define NSV  8              // seqs per WG
#define NWG  (BTn / NSV)    // 256 workgroups
#define NT   1024           // 16 waves
#define HROW 272            // padded LDS row stride (floats) for h
#define SROW 260            // padded LDS row stride for score stage

// physical index within an h row: +4 float skew per 64-chunk (conflict-free quads)
__device__ __forceinline__ int hp(int k) { return k + 4 * (k >> 6); }

__device__ __forceinline__ float sigf(float x) { return 1.0f / (1.0f + expf(-x)); }
__device__ __forceinline__ unsigned long long amax_key(float sc, int v) {
    unsigned fb = __float_as_uint(sc);
    fb = (fb & 0x80000000u) ? ~fb : (fb | 0x80000000u);   // order-preserving
    return ((unsigned long long)fb << 32) | (unsigned)(Vn - 1 - v);  // first-idx tie
}
__device__ __forceinline__ float dot4(float4 a, float4 b, float acc) {
    return fmaf(a.x, b.x, fmaf(a.y, b.y, fmaf(a.z, b.z, fmaf(a.w, b.w, acc))));
}

// Butterfly reduce-scatter over the 4 K-chunk lanes (ch = lane&3).
// In: v[0..7] = partial sums for seqs 0..7 (this lane's K-chunk).
// Out: a = full sum for seq 2ch, b = full sum for seq 2ch+1. Static regs only.
__device__ __forceinline__ void rs8(const float v[8], int ch, float& a, float& b) {
    const bool hi2 = (ch & 2) != 0;
    float w0, w1, w2, w3;
    { float s = hi2 ? v[0] : v[4]; float r = __shfl_xor(s, 2, 64); w0 = (hi2 ? v[4] : v[0]) + r; }
    { float s = hi2 ? v[1] : v[5]; float r = __shfl_xor(s, 2, 64); w1 = (hi2 ? v[5] : v[1]) + r; }
    { float s = hi2 ? v[2] : v[6]; float r = __shfl_xor(s, 2, 64); w2 = (hi2 ? v[6] : v[2]) + r; }
    { float s = hi2 ? v[3] : v[7]; float r = __shfl_xor(s, 2, 64); w3 = (hi2 ? v[7] : v[3]) + r; }
    const bool hi1 = (ch & 1) != 0;
    { float s = hi1 ? w0 : w2; float r = __shfl_xor(s, 1, 64); a = (hi1 ? w2 : w0) + r; }
    { float s = hi1 ? w1 : w3; float r = __shfl_xor(s, 1, 64); b = (hi1 ? w3 : w1) + r; }
}

// ---------------- precompute kernels ----------------

// Ptu[v*256+u] = float4{i,f,g,o}: emb[v]@Wih[g*256+u]^T + bih + bhh
__global__ void make_ptab(float4* __restrict__ Pp, const float* __restrict__ emb,
                          const float* __restrict__ Wih, const float* __restrict__ bih,
                          const float* __restrict__ bhh) {
    int v = blockIdx.x, u = threadIdx.x;
    __shared__ __align__(16) float es[En];
    if (u < En) es[u] = emb[v * En + u];
    __syncthreads();
    float a[4];
#pragma unroll
    for (int g = 0; g < 4; ++g) {
        int r = g * Hn + u;
        float acc = bih[r] + bhh[r];
        const float4* w4 = (const float4*)(Wih + r * En);
        const float4* e4 = (const float4*)es;
        for (int k = 0; k < En / 4; ++k) acc = dot4(w4[k], e4[k], acc);
        a[g] = acc;
    }
    Pp[v * Hn + u] = make_float4(a[0], a[1], a[2], a[3]);
}

// Wr[(j4*4+g)*1024 + (u*4+ch)] = float4{ Whh[g*256+u][ch*64+4j4 .. +3] }. 65536 f4.
__global__ void pack_wr(float4* __restrict__ Wr, const float* __restrict__ W) {
    int idx = blockIdx.x * 256 + threadIdx.x;
    int l = idx & 1023, stripe = idx >> 10;     // stripe 0..63
    int j4 = stripe >> 2, g = stripe & 3;
    int u = l >> 2, ch = l & 3;
    const float* s = W + (g * Hn + u) * Hn + ch * 64 + 4 * j4;
    Wr[idx] = make_float4(s[0], s[1], s[2], s[3]);
}

// Fr[j4*1024 + (u*4+ch)] = float4{ fcW[u][ch*64+4j4 .. +3] }. 16384 f4.
__global__ void pack_fr(float4* __restrict__ Fr, const float* __restrict__ W) {
    int idx = blockIdx.x * 256 + threadIdx.x;
    int l = idx & 1023, j4 = idx >> 10;
    int u = l >> 2, ch = l & 3;
    const float* s = W + u * Hn + ch * 64 + 4 * j4;
    Fr[idx] = make_float4(s[0], s[1], s[2], s[3]);
}

// ---------------- encoder ----------------
// 256 WGs x 1024 thr. Thread (u=tid>>2, ch=tid&3): gate rows 4u..4u+3 over
// K-chunk ch for all 8 seqs; reduce-scatter -> seqs {2ch,2ch+1} lane-local.
__global__ __launch_bounds__(NT, 4) void enc_kernel(
    const float4* __restrict__ Wr, const float4* __restrict__ Ptu,
    const int* __restrict__ phon, const int* __restrict__ lens,
    float* __restrict__ h0dec) {
    const int tid = threadIdx.x, wg = blockIdx.x;
    const int u = tid >> 2, ch = tid & 3;
    const int sA = 2 * ch, sB = 2 * ch + 1;
    __shared__ __align__(16) float hs[NSV * HROW];
    __shared__ int lsh[NSV];

    for (int i = tid; i < NSV * HROW; i += NT) hs[i] = 0.0f;
    if (tid < NSV) lsh[tid] = lens[wg * NSV + tid];
    float cA = 0.f, cB = 0.f;
    __syncthreads();
    int mx = 0;
#pragma unroll
    for (int i = 0; i < NSV; ++i) mx = max(mx, lsh[i]);
    const int lenA = lsh[sA], lenB = lsh[sB];

    for (int t = 0; t < mx; ++t) {
        const int tokA = phon[(wg * NSV + sA) * TPn + t];
        const int tokB = phon[(wg * NSV + sB) * TPn + t];
        const float4 pA = Ptu[tokA * Hn + u];      // prefetched; hidden by K-loop
        const float4 pB = Ptu[tokB * Hn + u];
        float ag[4][8];
#pragma unroll
        for (int g = 0; g < 4; ++g)
#pragma unroll
            for (int s = 0; s < 8; ++s) ag[g][s] = 0.0f;
        const float* hb = hs + ch * 68;
#pragma unroll 4
        for (int j4 = 0; j4 < 16; ++j4) {
            float4 w0 = Wr[(j4 * 4 + 0) * NT + tid];
            float4 w1 = Wr[(j4 * 4 + 1) * NT + tid];
            float4 w2 = Wr[(j4 * 4 + 2) * NT + tid];
            float4 w3 = Wr[(j4 * 4 + 3) * NT + tid];
#pragma unroll
            for (int s = 0; s < 8; ++s) {
                float4 hv = *(const float4*)&hb[s * HROW + 4 * j4];
                ag[0][s] = dot4(w0, hv, ag[0][s]);
                ag[1][s] = dot4(w1, hv, ag[1][s]);
                ag[2][s] = dot4(w2, hv, ag[2][s]);
                ag[3][s] = dot4(w3, hv, ag[3][s]);
            }
        }
        float gA[4], gB[4];
#pragma unroll
        for (int g = 0; g < 4; ++g) rs8(ag[g], ch, gA[g], gB[g]);
        __syncthreads();   // all K-reads of hs done
        float hA, hB;
        {
            float gi = sigf(gA[0] + pA.x), gf = sigf(gA[1] + pA.y);
            float gg = tanhf(gA[2] + pA.z), go = sigf(gA[3] + pA.w);
            cA = fmaf(gf, cA, gi * gg); hA = go * tanhf(cA);
        }
        {
            float gi = sigf(gB[0] + pB.x), gf = sigf(gB[1] + pB.y);
            float gg = tanhf(gB[2] + pB.z), go = sigf(gB[3] + pB.w);
            cB = fmaf(gf, cB, gi * gg); hB = go * tanhf(cB);
        }
        const int pu = hp(u);
        hs[sA * HROW + pu] = hA;
        hs[sB * HROW + pu] = hB;
        if (t == lenA - 1) h0dec[(wg * NSV + sA) * Hn + u] = hA;
        if (t == lenB - 1) h0dec[(wg * NSV + sB) * Hn + u] = hB;
        __syncthreads();   // new h visible
    }
}

// ---------------- decoder ----------------
// Iteration i: fc(h_i) -> scores_{i-1} -> argmax -> tok_i; gates(h_i,tok_i) -> h_{i+1}.
__global__ __launch_bounds__(NT, 4) void dec_kernel(
    const float4* __restrict__ Wr, const float4* __restrict__ Fr,
    const float4* __restrict__ Ptu, const float* __restrict__ fcb,
    const float* __restrict__ h0dec, const int* __restrict__ sosp,
    float* __restrict__ out) {
    const int tid = threadIdx.x, wg = blockIdx.x;
    const int u = tid >> 2, ch = tid & 3;
    const int sA = 2 * ch, sB = 2 * ch + 1;
    const int wv = tid >> 6, ln = tid & 63;
    __shared__ __align__(16) float hs[NSV * HROW];
    __shared__ __align__(16) float scx[NSV * SROW];
    __shared__ unsigned long long kex[16][NSV];
    __shared__ int toks[NSV];

    {   // stage h0
        int s = tid >> 7, k = (tid & 127) * 2;
        float2 v = *(const float2*)&h0dec[(wg * NSV + s) * Hn + k];
        int pk = hp(k);
        hs[s * HROW + pk] = v.x;
        hs[s * HROW + pk + 1] = v.y;
    }
    if (tid < NSV) toks[tid] = sosp[0];
    const float fb = fcb[u];
    float cA = 0.f, cB = 0.f;
    __syncthreads();

    for (int i = 0; i <= TPn; ++i) {
        const bool full = (i < TPn);
        float ag[4][8], af[8];
#pragma unroll
        for (int g = 0; g < 4; ++g)
#pragma unroll
            for (int s = 0; s < 8; ++s) ag[g][s] = 0.0f;
#pragma unroll
        for (int s = 0; s < 8; ++s) af[s] = 0.0f;
        const float* hb = hs + ch * 68;
        if (full) {
#pragma unroll 4
            for (int j4 = 0; j4 < 16; ++j4) {
                float4 w0 = Wr[(j4 * 4 + 0) * NT + tid];
                float4 w1 = Wr[(j4 * 4 + 1) * NT + tid];
                float4 w2 = Wr[(j4 * 4 + 2) * NT + tid];
                float4 w3 = Wr[(j4 * 4 + 3) * NT + tid];
                float4 f = Fr[j4 * NT + tid];
#pragma unroll
                for (int s = 0; s < 8; ++s) {
                    float4 hv = *(const float4*)&hb[s * HROW + 4 * j4];
                    ag[0][s] = dot4(w0, hv, ag[0][s]);
                    ag[1][s] = dot4(w1, hv, ag[1][s]);
                    ag[2][s] = dot4(w2, hv, ag[2][s]);
                    ag[3][s] = dot4(w3, hv, ag[3][s]);
                    af[s] = dot4(f, hv, af[s]);
                }
            }
        } else {   // last iteration: fc only
#pragma unroll 4
            for (int j4 = 0; j4 < 16; ++j4) {
                float4 f = Fr[j4 * NT + tid];
#pragma unroll
                for (int s = 0; s < 8; ++s) {
                    float4 hv = *(const float4*)&hb[s * HROW + 4 * j4];
                    af[s] = dot4(f, hv, af[s]);
                }
            }
        }
        float gA[4], gB[4], fA, fB;
#pragma unroll
        for (int g = 0; g < 4; ++g) rs8(ag[g], ch, gA[g], gB[g]);
        rs8(af, ch, fA, fB);

        if (i > 0) {   // scores_{i-1} for v=u, seqs sA,sB
            float scA = fA + fb, scB = fB + fb;
            scx[sA * SROW + u] = scA;
            scx[sB * SROW + u] = scB;
            unsigned long long kA = amax_key(scA, u);
            unsigned long long kB = amax_key(scB, u);
#pragma unroll
            for (int off = 4; off < 64; off <<= 1) {
                unsigned long long oA = __shfl_xor(kA, off, 64);
                unsigned long long oB = __shfl_xor(kB, off, 64);
                if (oA > kA) kA = oA;
                if (oB > kB) kB = oB;
            }
            if (ln < 4) {          // ln==ch here
                kex[wv][sA] = kA;
                kex[wv][sB] = kB;
            }
        }
        __syncthreads();   // hs reads done; scx/kex published

        if (i > 0) {
            if (tid < NSV) {       // global argmax per seq
                unsigned long long k = kex[0][tid];
#pragma unroll
                for (int w = 1; w < 16; ++w)
                    if (kex[w][tid] > k) k = kex[w][tid];
                toks[tid] = (Vn - 1) - (int)(k & 0xffffffffu);
            }
            {   // coalesced out store of scores_{i-1}
                int s = tid >> 7, k = (tid & 127) * 2;
                float2 v = *(const float2*)&scx[s * SROW + k];
                *(float2*)&out[((long)(wg * NSV + s) * TPn + (i - 1)) * Vn + k] = v;
            }
        }
        __syncthreads();   // toks visible

        if (full) {
            const int tokA = toks[sA], tokB = toks[sB];
            const float4 pA = Ptu[tokA * Hn + u];
            const float4 pB = Ptu[tokB * Hn + u];
            float hA, hB;
            {
                float gi = sigf(gA[0] + pA.x), gf = sigf(gA[1] + pA.y);
                float gg = tanhf(gA[2] + pA.z), go = sigf(gA[3] + pA.w);
                cA = fmaf(gf, cA, gi * gg); hA = go * tanhf(cA);
            }
            {
                float gi = sigf(gB[0] + pB.x), gf = sigf(gB[1] + pB.y);
                float gg = tanhf(gB[2] + pB.z), go = sigf(gB[3] + pB.w);
                cB = fmaf(gf, cB, gi * gg); hB = go * tanhf(cB);
            }
            const int pu = hp(u);
            hs[sA * HROW + pu] = hA;
            hs[sB * HROW + pu] = hB;
        }
        __syncthreads();   // new h visible
    }
}

// ---------------- launch ----------------
extern "C" void kernel_launch(void* const* d_in, const int* in_sizes, int n_in,
                              void* d_out, int out_size, void* d_ws, size_t ws_size,
                              hipStream_t stream) {
    const int*   phon = (const int*)d_in[0];
    const int*   lens = (const int*)d_in[1];
    const float* emb  = (const float*)d_in[2];
    const float* eWih = (const float*)d_in[3];
    const float* eWhh = (const float*)d_in[4];
    const float* ebih = (const float*)d_in[5];
    const float* ebhh = (const float*)d_in[6];
    const float* dWih = (const float*)d_in[7];
    const float* dWhh = (const float*)d_in[8];
    const float* dbih = (const float*)d_in[9];
    const float* dbhh = (const float*)d_in[10];
    const float* fcW  = (const float*)d_in[11];
    const float* fcb  = (const float*)d_in[12];
    const int*   sos  = (const int*)d_in[13];
    float* out = (float*)d_out;

    float4* Ptu_e = (float4*)d_ws;           // 65536 f4 = 1 MB
    float4* Ptu_d = Ptu_e + 65536;           // 1 MB
    float4* Wr_e  = Ptu_d + 65536;           // 1 MB
    float4* Wr_d  = Wr_e + 65536;            // 1 MB
    float4* Fr    = Wr_d + 65536;            // 256 KB
    float*  h0d   = (float*)(Fr + 16384);    // 2 MB

    make_ptab<<<256, 256, 0, stream>>>(Ptu_e, emb, eWih, ebih, ebhh);
    make_ptab<<<256, 256, 0, stream>>>(Ptu_d, emb, dWih, dbih, dbhh);
    pack_wr<<<256, 256, 0, stream>>>(Wr_e, eWhh);
    pack_wr<<<256, 256, 0, stream>>>(Wr_d, dWhh);
    pack_fr<<<64, 256, 0, stream>>>(Fr, fcW);
    enc_kernel<<<NWG, NT, 0, stream>>>(Wr_e, Ptu_e, phon, lens, h0d);
    dec_kernel<<<NWG, NT, 0, stream>>>(Wr_d, Fr, Ptu_d, fcb, h0d, sos, out);
}